// Round 16
// baseline (123.693 us; speedup 1.0000x reference)
//
#include <hip/hip_runtime.h>

#define N_ROWS 32768
#define DIM    256
#define KCODES 2048
#define CSCALE 4096.0f
#define BROWS  64            // rows per block; each wave covers ALL 64 rows

typedef __attribute__((ext_vector_type(16))) float f32x16;
typedef __attribute__((ext_vector_type(8)))  int   i32x8;
typedef __attribute__((ext_vector_type(4)))  unsigned int u32x4;

union frag32 { i32x8 v8; u32x4 q[2]; };   // 32B: one MX-MFMA operand (8 VGPR)

// pack 16 fp32 -> 16 fp8 e4m3 (4 dwords)
__device__ __forceinline__ uint4 pack16(const float* s) {
    int a = __builtin_amdgcn_cvt_pk_fp8_f32(s[0],  s[1],  0, false);
    a     = __builtin_amdgcn_cvt_pk_fp8_f32(s[2],  s[3],  a, true);
    int b = __builtin_amdgcn_cvt_pk_fp8_f32(s[4],  s[5],  0, false);
    b     = __builtin_amdgcn_cvt_pk_fp8_f32(s[6],  s[7],  b, true);
    int c = __builtin_amdgcn_cvt_pk_fp8_f32(s[8],  s[9],  0, false);
    c     = __builtin_amdgcn_cvt_pk_fp8_f32(s[10], s[11], c, true);
    int d = __builtin_amdgcn_cvt_pk_fp8_f32(s[12], s[13], 0, false);
    d     = __builtin_amdgcn_cvt_pk_fp8_f32(s[14], s[15], d, true);
    uint4 o; o.x = a; o.y = b; o.z = c; o.w = d;
    return o;
}

// ---------------- prologue 1: half-codenorm + loss init ------------------------
__global__ void prep_h(const float* __restrict__ cb,
                       float* __restrict__ halfcn, float* __restrict__ loss) {
    const int t    = threadIdx.x;            // 256 thr = 4 codes x 64 slots
    const int code = blockIdx.x * 4 + (t >> 6);
    const int s    = t & 63;
    if (blockIdx.x == 0 && t == 0) *loss = 0.0f;
    const int k0 = s * 4;
    float4 v = *(const float4*)&cb[(size_t)code * DIM + k0];
    float ssum = v.x * v.x + v.y * v.y + v.z * v.z + v.w * v.w;
    #pragma unroll
    for (int o = 32; o > 0; o >>= 1) ssum += __shfl_down(ssum, o, 64);
    if (s == 0) halfcn[code] = 0.5f * CSCALE * ssum;
}

// ---------------- prologue 2: codebook -> MX fragment-major fp8 buffer ---------
// 64 tiles of 32 codes. Unit (tile, c, u, L) = 16B at byte offset
// tile*8192 + c*2048 + u*1024 + L*16. Lane L (l32=L&31, h=L>>5) holds
// code = tile*32 + l32, k = c*64 + h*32 + u*16 + [0,16). A and B both store
// 32 consecutive k-bytes per (h, chunk) -> any internal HW k-permutation
// cancels in the dot product (A/B symmetric k-maps).
__global__ void prep_frag(const float* __restrict__ cb, uint4* __restrict__ cbF) {
    const int gid  = blockIdx.x * 256 + threadIdx.x;  // [0, 32768)
    const int tile = gid >> 9;
    const int r9   = gid & 511;
    const int c    = r9 >> 7;
    const int r7   = r9 & 127;
    const int u    = r7 >> 6;
    const int L    = r7 & 63;
    const int l32  = L & 31, h = L >> 5;
    const int code = tile * 32 + l32;
    const int k0   = c * 64 + h * 32 + u * 16;
    float buf[16];
    #pragma unroll
    for (int b = 0; b < 4; b++) {
        float4 v = *(const float4*)&cb[(size_t)code * DIM + k0 + b * 4];
        buf[b * 4 + 0] = v.x * CSCALE; buf[b * 4 + 1] = v.y * CSCALE;
        buf[b * 4 + 2] = v.z * CSCALE; buf[b * 4 + 3] = v.w * CSCALE;
    }
    cbF[gid] = pack16(buf);
}

// ---------------- fused: argmin over all 2048 codes + gather + loss -------------
// r6..r14 invariant: wall tracks MFMA INSTRUCTION count (b ~ 121 cyc/instr), not
// occupancy / B-source / ring depth / wait-point count. This round: 4x fewer
// MFMA instructions via MX-scaled mfma_scale_f32_32x32x64_f8f6f4 (K=64, 2x rate,
// scales = E8M0 127 = x1.0). 16 code-tiles/wave x {8 loads of 1KB, 8 MFMA, fold}.
// A resident in 64 VGPRs; B ring-2 over tiles (64 VGPRs). Same numerics
// (fp8 e4m3, cb x4096, -0.5||c||^2 bias in acc init).
__global__ __launch_bounds__(256, 2) void vq_fused(
        const float* __restrict__ x, const float* __restrict__ cb,
        const uint4* __restrict__ cbF, const float* __restrict__ halfcn,
        float* __restrict__ out, float* __restrict__ loss) {
    __shared__ char As[2][8192];      // [rt][32 rows x 256B], 16B-granule XOR swizzle
    __shared__ float hcs[KCODES];     // per-code bias (0.5*CSCALE*||c||^2)
    struct Tail { float red[BROWS][4]; int idxs[BROWS]; float lred[4]; };
    Tail* tl = (Tail*)As;             // overlay: As dead after A->reg read

    const int t    = threadIdx.x;
    const int lane = t & 63;
    const int w    = t >> 6;          // wave = 16-tile code slice (512 codes)
    const int l32  = lane & 31;
    const int h    = lane >> 5;
    const int row0 = blockIdx.x * BROWS;
    char* asb = &As[0][0];

    // ---- stage A once: fp32 -> fp8 e4m3, k-order rows, XOR-swizzled LDS ----
    {
        const int r  = t >> 2;               // 0..63
        const int q4 = t & 3;                // 64B quarter of the 256B row
        const int rt = r >> 5, rw = r & 31;
        const float* src = x + (size_t)(row0 + r) * DIM;
        float buf[16];
        #pragma unroll
        for (int g = 0; g < 4; g++) {
            const int o16 = q4 * 4 + g;      // granule index in k-order
            #pragma unroll
            for (int j = 0; j < 4; j++)
                *(float4*)(buf + j * 4) = *(const float4*)(src + o16 * 16 + j * 4);
            *(uint4*)(asb + rt * 8192 + rw * 256 + ((o16 ^ (rw & 7)) << 4)) = pack16(buf);
        }
        #pragma unroll
        for (int jj = 0; jj < 8; jj++) hcs[jj * 256 + t] = halfcn[jj * 256 + t];
    }

    float mp[2][16];                  // [rt][r]
    #pragma unroll
    for (int rt = 0; rt < 2; rt++)
        #pragma unroll
        for (int r = 0; r < 16; r++) mp[rt][r] = -3.0e38f;

    // B prefetch base (fully coalesced 1KB loads)
    const char* bbase = (const char*)cbF + (size_t)(w * 16) * 8192 + (size_t)lane * 16;

    // ring-2 over tiles: prefetch tiles 0,1 (16 loads) BEFORE the barrier
    frag32 bfr[2][4];                 // [slot][chunk c]
    #pragma unroll
    for (int s = 0; s < 2; s++)
        #pragma unroll
        for (int c = 0; c < 4; c++)
            #pragma unroll
            for (int u = 0; u < 2; u++)
                bfr[s][c].q[u] = *(const u32x4*)(bbase + s * 8192 + c * 2048 + u * 1024);

    __syncthreads();                  // As + hcs visible

    // A fragments -> registers: afr[c][rt] = rows (rt*32+l32), k in [c*64+h*32,+32)
    frag32 afr[4][2];                 // 64 VGPRs; As dead afterwards
    #pragma unroll
    for (int c = 0; c < 4; c++)
        #pragma unroll
        for (int rt = 0; rt < 2; rt++)
            #pragma unroll
            for (int u = 0; u < 2; u++) {
                const int o16 = c * 4 + h * 2 + u;
                afr[c][rt].q[u] = *(const u32x4*)(
                    asb + rt * 8192 + l32 * 256 + ((o16 ^ (l32 & 7)) << 4));
            }

    #pragma unroll
    for (int tt = 0; tt < 16; ++tt) {
        const int sl = tt & 1;        // literal per unroll
        const float hc = hcs[(w * 16 + tt) * 32 + l32];
        f32x16 acc[2];                // [rt]; all elements are col=l32 -> same code
        #pragma unroll
        for (int r = 0; r < 16; r++) { acc[0][r] = -hc; acc[1][r] = -hc; }

        // 8 MX MFMAs (K=64 each): 2 chains x 4 deep, interleaved
        #pragma unroll
        for (int c = 0; c < 4; c++)
            #pragma unroll
            for (int rt = 0; rt < 2; rt++)
                acc[rt] = __builtin_amdgcn_mfma_scale_f32_32x32x64_f8f6f4(
                    afr[c][rt].v8, bfr[sl][c].v8, acc[rt],
                    0, 0,            // cbsz/blgp: fp8 e4m3 both
                    0, 127,          // opsel_a, scale_a = 2^0
                    0, 127);         // opsel_b, scale_b = 2^0

        // refill slot with tile tt+2 (after reads; SSA renames)
        if (tt + 2 < 16) {
            #pragma unroll
            for (int c = 0; c < 4; c++)
                #pragma unroll
                for (int u = 0; u < 2; u++)
                    bfr[sl][c].q[u] = *(const u32x4*)(
                        bbase + (tt + 2) * 8192 + c * 2048 + u * 1024);
        }

        // fold tile into running max (pack 11-bit code id into low mantissa)
        const unsigned code = (unsigned)((w * 16 + tt) * 32 + l32);
        #pragma unroll
        for (int rt = 0; rt < 2; rt++)
            #pragma unroll
            for (int r = 0; r < 16; r++) {
                unsigned u = (__float_as_uint(acc[rt][r]) & 0xFFFFF800u) | code;
                mp[rt][r] = fmaxf(mp[rt][r], __uint_as_float(u));
            }
    }

    // ---- cross-lane argmax over the 32 lanes sharing each output row ----
    #pragma unroll
    for (int m = 1; m <= 16; m <<= 1)
        #pragma unroll
        for (int rt = 0; rt < 2; rt++)
            #pragma unroll
            for (int r = 0; r < 16; r++)
                mp[rt][r] = fmaxf(mp[rt][r], __shfl_xor(mp[rt][r], m, 64));

    __syncthreads();                  // everyone past As reads (overlay safe)

    if (l32 == 0) {
        #pragma unroll
        for (int rt = 0; rt < 2; rt++)
            #pragma unroll
            for (int r = 0; r < 16; r++) {
                const int row = rt * 32 + (r & 3) + 8 * (r >> 2) + 4 * h;   // 0..63
                tl->red[row][w] = mp[rt][r];
            }
    }
    __syncthreads();
    if (t < BROWS) {
        float b0 = fmaxf(fmaxf(tl->red[t][0], tl->red[t][1]),
                         fmaxf(tl->red[t][2], tl->red[t][3]));
        tl->idxs[t] = (int)(__float_as_uint(b0) & 2047u);
    }
    __syncthreads();

    // ---- fused gather (fp32 codebook) + loss partial ----
    float lsum = 0.0f;
    #pragma unroll 4
    for (int r = 0; r < BROWS; r++) {
        const int code = tl->idxs[r];
        const float c  = cb[(size_t)code * DIM + t];
        const float xv = x[(size_t)(row0 + r) * DIM + t];
        out[(size_t)(row0 + r) * DIM + t] = c;
        const float d = xv - c;
        lsum += d * d;
    }
    #pragma unroll
    for (int o = 32; o > 0; o >>= 1) lsum += __shfl_down(lsum, o, 64);
    if (lane == 0) tl->lred[w] = lsum;
    __syncthreads();
    if (t == 0) {
        const float scale = 1.25f / (float)((size_t)N_ROWS * DIM);  // (beta+1)/(N*D)
        atomicAdd(loss, (tl->lred[0] + tl->lred[1] + tl->lred[2] + tl->lred[3]) * scale);
    }
}

extern "C" void kernel_launch(void* const* d_in, const int* in_sizes, int n_in,
                              void* d_out, int out_size, void* d_ws, size_t ws_size,
                              hipStream_t stream) {
    const float* x  = (const float*)d_in[0];
    const float* cb = (const float*)d_in[1];
    float* out  = (float*)d_out;
    float* loss = out + (size_t)N_ROWS * DIM;

    char* ws = (char*)d_ws;
    uint4* cbF    = (uint4*)ws;                                    // 512 KB
    float* halfcn = (float*)(ws + (size_t)KCODES * 256);           // 8 KB

    prep_h   <<<KCODES / 4, 256, 0, stream>>>(cb, halfcn, loss);
    prep_frag<<<128,        256, 0, stream>>>(cb, cbF);
    vq_fused <<<N_ROWS / BROWS, 256, 0, stream>>>(x, cb, cbF, halfcn, out, loss);
}

// Round 21
// 120.297 us; speedup vs baseline: 1.0282x; 1.0282x over previous
//
#include <hip/hip_runtime.h>

#define N_ROWS 32768
#define DIM    256
#define KCODES 2048
#define CSCALE 4096.0f
#define BROWS  64            // rows per block; each wave covers ALL 64 rows

typedef __attribute__((ext_vector_type(16))) float f32x16;
typedef __attribute__((ext_vector_type(8)))  int   i32x8;
typedef __attribute__((ext_vector_type(4)))  unsigned int u32x4;

union frag32 { i32x8 v8; u32x4 q[2]; };   // 32B: one MX-MFMA operand (8 VGPR)

// pack 16 fp32 -> 16 fp8 e4m3 (4 dwords)
__device__ __forceinline__ uint4 pack16(const float* s) {
    int a = __builtin_amdgcn_cvt_pk_fp8_f32(s[0],  s[1],  0, false);
    a     = __builtin_amdgcn_cvt_pk_fp8_f32(s[2],  s[3],  a, true);
    int b = __builtin_amdgcn_cvt_pk_fp8_f32(s[4],  s[5],  0, false);
    b     = __builtin_amdgcn_cvt_pk_fp8_f32(s[6],  s[7],  b, true);
    int c = __builtin_amdgcn_cvt_pk_fp8_f32(s[8],  s[9],  0, false);
    c     = __builtin_amdgcn_cvt_pk_fp8_f32(s[10], s[11], c, true);
    int d = __builtin_amdgcn_cvt_pk_fp8_f32(s[12], s[13], 0, false);
    d     = __builtin_amdgcn_cvt_pk_fp8_f32(s[14], s[15], d, true);
    uint4 o; o.x = a; o.y = b; o.z = c; o.w = d;
    return o;
}

// ---------------- merged prologue: halfcn + loss init + cbF (one launch) -------
// grid 512 x 256. All blocks: halfcn for 4 codes (64-lane reduction each).
// Blocks 0..127 additionally emit the MX fragment-major fp8 buffer:
// unit (tile, c, u, L) = 16B at byte offset tile*8192 + c*2048 + u*1024 + L*16;
// lane L (l32=L&31, h=L>>5) holds code = tile*32+l32, k = c*64+h*32+u*16+[0,16).
// A and B both store 32 consecutive k-bytes per (h, chunk) -> internal HW
// k-permutations cancel in the dot product (A/B symmetric k-maps).
__global__ void prep_all(const float* __restrict__ cb, uint4* __restrict__ cbF,
                         float* __restrict__ halfcn, float* __restrict__ loss) {
    const int t    = threadIdx.x;
    if (blockIdx.x == 0 && t == 0) *loss = 0.0f;
    {   // ---- halfcn part (4 codes/block) ----
        const int code = blockIdx.x * 4 + (t >> 6);
        const int s    = t & 63;
        float4 v = *(const float4*)&cb[(size_t)code * DIM + s * 4];
        float ssum = v.x * v.x + v.y * v.y + v.z * v.z + v.w * v.w;
        #pragma unroll
        for (int o = 32; o > 0; o >>= 1) ssum += __shfl_down(ssum, o, 64);
        if (s == 0) halfcn[code] = 0.5f * CSCALE * ssum;
    }
    if (blockIdx.x < 128) {   // ---- cbF part ----
        const int gid  = blockIdx.x * 256 + t;        // [0, 32768)
        const int tile = gid >> 9;
        const int r9   = gid & 511;
        const int c    = r9 >> 7;
        const int r7   = r9 & 127;
        const int u    = r7 >> 6;
        const int L    = r7 & 63;
        const int l32  = L & 31, h = L >> 5;
        const int code = tile * 32 + l32;
        const int k0   = c * 64 + h * 32 + u * 16;
        float buf[16];
        #pragma unroll
        for (int b = 0; b < 4; b++) {
            float4 v = *(const float4*)&cb[(size_t)code * DIM + k0 + b * 4];
            buf[b * 4 + 0] = v.x * CSCALE; buf[b * 4 + 1] = v.y * CSCALE;
            buf[b * 4 + 2] = v.z * CSCALE; buf[b * 4 + 3] = v.w * CSCALE;
        }
        cbF[gid] = pack16(buf);
    }
}

// ---------------- fused: argmin over all 2048 codes + gather + loss -------------
// r16 lesson: MX cut MFMA instrs 4x but spilled (~60B/thread scratch: WRITE
// +7.7MB, VGPR pinned 128). Round 17: (1) launch_bounds (256,1) -> allocator cap
// 512; demand ~240 lands <=256 so HW still fits 2 waves/SIMD, spill gone.
// (2) deferred fold: tile tt's MFMAs (matrix pipe) run while tile tt-1's fold
// (VALU) executes from the OTHER accumulator (accA/accB, literal parity) --
// breaks the chain->fold->init serialization. 16 tiles x {8 MX MFMA K=64}.
__global__ __launch_bounds__(256, 1) void vq_fused(
        const float* __restrict__ x, const float* __restrict__ cb,
        const uint4* __restrict__ cbF, const float* __restrict__ halfcn,
        float* __restrict__ out, float* __restrict__ loss) {
    __shared__ char As[2][8192];      // [rt][32 rows x 256B], 16B-granule XOR swizzle
    __shared__ float hcs[KCODES];     // per-code bias (0.5*CSCALE*||c||^2)
    struct Tail { float red[BROWS][4]; int idxs[BROWS]; float lred[4]; };
    Tail* tl = (Tail*)As;             // overlay: As dead after A->reg read

    const int t    = threadIdx.x;
    const int lane = t & 63;
    const int w    = t >> 6;          // wave = 16-tile code slice (512 codes)
    const int l32  = lane & 31;
    const int h    = lane >> 5;
    const int row0 = blockIdx.x * BROWS;
    char* asb = &As[0][0];

    // ---- stage A once: fp32 -> fp8 e4m3, k-order rows, XOR-swizzled LDS ----
    {
        const int r  = t >> 2;               // 0..63
        const int q4 = t & 3;                // 64B quarter of the 256B row
        const int rt = r >> 5, rw = r & 31;
        const float* src = x + (size_t)(row0 + r) * DIM;
        float buf[16];
        #pragma unroll
        for (int g = 0; g < 4; g++) {
            const int o16 = q4 * 4 + g;      // granule index in k-order
            #pragma unroll
            for (int j = 0; j < 4; j++)
                *(float4*)(buf + j * 4) = *(const float4*)(src + o16 * 16 + j * 4);
            *(uint4*)(asb + rt * 8192 + rw * 256 + ((o16 ^ (rw & 7)) << 4)) = pack16(buf);
        }
        #pragma unroll
        for (int jj = 0; jj < 8; jj++) hcs[jj * 256 + t] = halfcn[jj * 256 + t];
    }

    float mp[2][16];                  // [rt][r]
    #pragma unroll
    for (int rt = 0; rt < 2; rt++)
        #pragma unroll
        for (int r = 0; r < 16; r++) mp[rt][r] = -3.0e38f;

    // B prefetch base (fully coalesced 1KB loads)
    const char* bbase = (const char*)cbF + (size_t)(w * 16) * 8192 + (size_t)lane * 16;

    // ring-2 over tiles: prefetch tiles 0,1 (16 loads) BEFORE the barrier
    frag32 bfr[2][4];                 // [slot][chunk c]
    #pragma unroll
    for (int s = 0; s < 2; s++)
        #pragma unroll
        for (int c = 0; c < 4; c++)
            #pragma unroll
            for (int u = 0; u < 2; u++)
                bfr[s][c].q[u] = *(const u32x4*)(bbase + s * 8192 + c * 2048 + u * 1024);

    __syncthreads();                  // As + hcs visible

    // A fragments -> registers: afr[c][rt] = rows (rt*32+l32), k in [c*64+h*32,+32)
    frag32 afr[4][2];                 // 64 VGPRs; As dead afterwards
    #pragma unroll
    for (int c = 0; c < 4; c++)
        #pragma unroll
        for (int rt = 0; rt < 2; rt++)
            #pragma unroll
            for (int u = 0; u < 2; u++) {
                const int o16 = c * 4 + h * 2 + u;
                afr[c][rt].q[u] = *(const u32x4*)(
                    asb + rt * 8192 + l32 * 256 + ((o16 ^ (l32 & 7)) << 4));
            }

    f32x16 accA[2], accB[2];

    auto initAcc = [&](f32x16* acc, int tt) {
        const float hc = hcs[(w * 16 + tt) * 32 + l32];
        #pragma unroll
        for (int r = 0; r < 16; r++) { acc[0][r] = -hc; acc[1][r] = -hc; }
    };
    auto mfmaTile = [&](f32x16* acc, int sl) {
        #pragma unroll
        for (int c = 0; c < 4; c++)
            #pragma unroll
            for (int rt = 0; rt < 2; rt++)
                acc[rt] = __builtin_amdgcn_mfma_scale_f32_32x32x64_f8f6f4(
                    afr[c][rt].v8, bfr[sl][c].v8, acc[rt],
                    0, 0, 0, 127, 0, 127);
    };
    auto refill = [&](int sl, int tile) {
        #pragma unroll
        for (int c = 0; c < 4; c++)
            #pragma unroll
            for (int u = 0; u < 2; u++)
                bfr[sl][c].q[u] = *(const u32x4*)(
                    bbase + tile * 8192 + c * 2048 + u * 1024);
    };
    auto fold = [&](const f32x16* acc, int tt) {
        const unsigned code = (unsigned)((w * 16 + tt) * 32 + l32);
        #pragma unroll
        for (int rt = 0; rt < 2; rt++)
            #pragma unroll
            for (int r = 0; r < 16; r++) {
                unsigned u = (__float_as_uint(acc[rt][r]) & 0xFFFFF800u) | code;
                mp[rt][r] = fmaxf(mp[rt][r], __uint_as_float(u));
            }
    };

    // tile 0 -> accA
    initAcc(accA, 0);
    mfmaTile(accA, 0);
    refill(0, 2);

    #pragma unroll
    for (int tt = 1; tt < 16; ++tt) {
        const int sl = tt & 1;        // literal per unroll
        if (tt & 1) { initAcc(accB, tt); mfmaTile(accB, sl); }
        else        { initAcc(accA, tt); mfmaTile(accA, sl); }
        if (tt + 2 < 16) refill(sl, tt + 2);
        // fold PREVIOUS tile (other acc) -- VALU overlaps cur tile's MFMAs
        if (tt & 1) fold(accA, tt - 1);
        else        fold(accB, tt - 1);
    }
    fold(accB, 15);                   // 15 is odd -> accB

    // ---- cross-lane argmax over the 32 lanes sharing each output row ----
    #pragma unroll
    for (int m = 1; m <= 16; m <<= 1)
        #pragma unroll
        for (int rt = 0; rt < 2; rt++)
            #pragma unroll
            for (int r = 0; r < 16; r++)
                mp[rt][r] = fmaxf(mp[rt][r], __shfl_xor(mp[rt][r], m, 64));

    __syncthreads();                  // everyone past As reads (overlay safe)

    if (l32 == 0) {
        #pragma unroll
        for (int rt = 0; rt < 2; rt++)
            #pragma unroll
            for (int r = 0; r < 16; r++) {
                const int row = rt * 32 + (r & 3) + 8 * (r >> 2) + 4 * h;   // 0..63
                tl->red[row][w] = mp[rt][r];
            }
    }
    __syncthreads();
    if (t < BROWS) {
        float b0 = fmaxf(fmaxf(tl->red[t][0], tl->red[t][1]),
                         fmaxf(tl->red[t][2], tl->red[t][3]));
        tl->idxs[t] = (int)(__float_as_uint(b0) & 2047u);
    }
    __syncthreads();

    // ---- fused gather (fp32 codebook) + loss partial ----
    float lsum = 0.0f;
    #pragma unroll 4
    for (int r = 0; r < BROWS; r++) {
        const int code = tl->idxs[r];
        const float c  = cb[(size_t)code * DIM + t];
        const float xv = x[(size_t)(row0 + r) * DIM + t];
        out[(size_t)(row0 + r) * DIM + t] = c;
        const float d = xv - c;
        lsum += d * d;
    }
    #pragma unroll
    for (int o = 32; o > 0; o >>= 1) lsum += __shfl_down(lsum, o, 64);
    if (lane == 0) tl->lred[w] = lsum;
    __syncthreads();
    if (t == 0) {
        const float scale = 1.25f / (float)((size_t)N_ROWS * DIM);  // (beta+1)/(N*D)
        atomicAdd(loss, (tl->lred[0] + tl->lred[1] + tl->lred[2] + tl->lred[3]) * scale);
    }
}

extern "C" void kernel_launch(void* const* d_in, const int* in_sizes, int n_in,
                              void* d_out, int out_size, void* d_ws, size_t ws_size,
                              hipStream_t stream) {
    const float* x  = (const float*)d_in[0];
    const float* cb = (const float*)d_in[1];
    float* out  = (float*)d_out;
    float* loss = out + (size_t)N_ROWS * DIM;

    char* ws = (char*)d_ws;
    uint4* cbF    = (uint4*)ws;                                    // 512 KB
    float* halfcn = (float*)(ws + (size_t)KCODES * 256);           // 8 KB

    prep_all<<<KCODES / 4, 256, 0, stream>>>(cb, cbF, halfcn, loss);
    vq_fused<<<N_ROWS / BROWS, 256, 0, stream>>>(x, cb, cbF, halfcn, out, loss);
}

// Round 22
// 120.256 us; speedup vs baseline: 1.0286x; 1.0003x over previous
//
#include <hip/hip_runtime.h>

#define N_ROWS 32768
#define DIM    256
#define KCODES 2048
#define CSCALE 4096.0f
#define BROWS  64            // rows per block; each wave covers ALL 64 rows

typedef __attribute__((ext_vector_type(16))) float f32x16;
typedef __attribute__((ext_vector_type(8)))  int   i32x8;
typedef __attribute__((ext_vector_type(4)))  unsigned int u32x4;

union frag32 { i32x8 v8; u32x4 q[2]; };   // 32B: one MX-MFMA operand (8 VGPR)

// pack 16 fp32 -> 16 fp8 e4m3 (4 dwords)
__device__ __forceinline__ uint4 pack16(const float* s) {
    int a = __builtin_amdgcn_cvt_pk_fp8_f32(s[0],  s[1],  0, false);
    a     = __builtin_amdgcn_cvt_pk_fp8_f32(s[2],  s[3],  a, true);
    int b = __builtin_amdgcn_cvt_pk_fp8_f32(s[4],  s[5],  0, false);
    b     = __builtin_amdgcn_cvt_pk_fp8_f32(s[6],  s[7],  b, true);
    int c = __builtin_amdgcn_cvt_pk_fp8_f32(s[8],  s[9],  0, false);
    c     = __builtin_amdgcn_cvt_pk_fp8_f32(s[10], s[11], c, true);
    int d = __builtin_amdgcn_cvt_pk_fp8_f32(s[12], s[13], 0, false);
    d     = __builtin_amdgcn_cvt_pk_fp8_f32(s[14], s[15], d, true);
    uint4 o; o.x = a; o.y = b; o.z = c; o.w = d;
    return o;
}

// ---------------- merged prologue: halfcn + loss init + cbF (one launch) -------
// MEASURED (r21): merging the two prep launches cut non-vq time ~72 -> ~32 us.
// grid 512 x 256. All blocks: halfcn for 4 codes. Blocks 0..127 also emit the
// MX fragment-major fp8 buffer: unit (tile, c, u, L) = 16B at byte offset
// tile*8192 + c*2048 + u*1024 + L*16; lane L (l32=L&31, h=L>>5) holds
// code = tile*32+l32, k = c*64+h*32+u*16+[0,16). A and B both store 32
// consecutive k-bytes per (h, chunk) -> internal HW k-permutations cancel.
__global__ void prep_all(const float* __restrict__ cb, uint4* __restrict__ cbF,
                         float* __restrict__ halfcn, float* __restrict__ loss) {
    const int t    = threadIdx.x;
    if (blockIdx.x == 0 && t == 0) *loss = 0.0f;
    {   // ---- halfcn part (4 codes/block) ----
        const int code = blockIdx.x * 4 + (t >> 6);
        const int s    = t & 63;
        float4 v = *(const float4*)&cb[(size_t)code * DIM + s * 4];
        float ssum = v.x * v.x + v.y * v.y + v.z * v.z + v.w * v.w;
        #pragma unroll
        for (int o = 32; o > 0; o >>= 1) ssum += __shfl_down(ssum, o, 64);
        if (s == 0) halfcn[code] = 0.5f * CSCALE * ssum;
    }
    if (blockIdx.x < 128) {   // ---- cbF part ----
        const int gid  = blockIdx.x * 256 + t;        // [0, 32768)
        const int tile = gid >> 9;
        const int r9   = gid & 511;
        const int c    = r9 >> 7;
        const int r7   = r9 & 127;
        const int u    = r7 >> 6;
        const int L    = r7 & 63;
        const int l32  = L & 31, h = L >> 5;
        const int code = tile * 32 + l32;
        const int k0   = c * 64 + h * 32 + u * 16;
        float buf[16];
        #pragma unroll
        for (int b = 0; b < 4; b++) {
            float4 v = *(const float4*)&cb[(size_t)code * DIM + k0 + b * 4];
            buf[b * 4 + 0] = v.x * CSCALE; buf[b * 4 + 1] = v.y * CSCALE;
            buf[b * 4 + 2] = v.z * CSCALE; buf[b * 4 + 3] = v.w * CSCALE;
        }
        cbF[gid] = pack16(buf);
    }
}

// ---------------- fused: argmin over all 2048 codes + gather + loss -------------
// r16 kernel VERBATIM (measured 48.3 us). r21 taught: the (256,2) spill (~60B/thr,
// WRITE +7.7MB) is CHEAPER than losing a resident block (r21: (256,1), VGPR 192,
// occupancy 10.4%, 88 us). Keep (256,2), single acc, inline fold.
// 16 code-tiles/wave x {8 loads of 1KB, 8 MX MFMA K=64, fold}. A resident in
// 64 VGPRs; B ring-2 over tiles. fp8 e4m3, cb x4096, -0.5||c||^2 bias in acc.
__global__ __launch_bounds__(256, 2) void vq_fused(
        const float* __restrict__ x, const float* __restrict__ cb,
        const uint4* __restrict__ cbF, const float* __restrict__ halfcn,
        float* __restrict__ out, float* __restrict__ loss) {
    __shared__ char As[2][8192];      // [rt][32 rows x 256B], 16B-granule XOR swizzle
    __shared__ float hcs[KCODES];     // per-code bias (0.5*CSCALE*||c||^2)
    struct Tail { float red[BROWS][4]; int idxs[BROWS]; float lred[4]; };
    Tail* tl = (Tail*)As;             // overlay: As dead after A->reg read

    const int t    = threadIdx.x;
    const int lane = t & 63;
    const int w    = t >> 6;          // wave = 16-tile code slice (512 codes)
    const int l32  = lane & 31;
    const int h    = lane >> 5;
    const int row0 = blockIdx.x * BROWS;
    char* asb = &As[0][0];

    // ---- stage A once: fp32 -> fp8 e4m3, k-order rows, XOR-swizzled LDS ----
    {
        const int r  = t >> 2;               // 0..63
        const int q4 = t & 3;                // 64B quarter of the 256B row
        const int rt = r >> 5, rw = r & 31;
        const float* src = x + (size_t)(row0 + r) * DIM;
        float buf[16];
        #pragma unroll
        for (int g = 0; g < 4; g++) {
            const int o16 = q4 * 4 + g;      // granule index in k-order
            #pragma unroll
            for (int j = 0; j < 4; j++)
                *(float4*)(buf + j * 4) = *(const float4*)(src + o16 * 16 + j * 4);
            *(uint4*)(asb + rt * 8192 + rw * 256 + ((o16 ^ (rw & 7)) << 4)) = pack16(buf);
        }
        #pragma unroll
        for (int jj = 0; jj < 8; jj++) hcs[jj * 256 + t] = halfcn[jj * 256 + t];
    }

    float mp[2][16];                  // [rt][r]
    #pragma unroll
    for (int rt = 0; rt < 2; rt++)
        #pragma unroll
        for (int r = 0; r < 16; r++) mp[rt][r] = -3.0e38f;

    // B prefetch base (fully coalesced 1KB loads)
    const char* bbase = (const char*)cbF + (size_t)(w * 16) * 8192 + (size_t)lane * 16;

    // ring-2 over tiles: prefetch tiles 0,1 (16 loads) BEFORE the barrier
    frag32 bfr[2][4];                 // [slot][chunk c]
    #pragma unroll
    for (int s = 0; s < 2; s++)
        #pragma unroll
        for (int c = 0; c < 4; c++)
            #pragma unroll
            for (int u = 0; u < 2; u++)
                bfr[s][c].q[u] = *(const u32x4*)(bbase + s * 8192 + c * 2048 + u * 1024);

    __syncthreads();                  // As + hcs visible

    // A fragments -> registers: afr[c][rt] = rows (rt*32+l32), k in [c*64+h*32,+32)
    frag32 afr[4][2];                 // 64 VGPRs; As dead afterwards
    #pragma unroll
    for (int c = 0; c < 4; c++)
        #pragma unroll
        for (int rt = 0; rt < 2; rt++)
            #pragma unroll
            for (int u = 0; u < 2; u++) {
                const int o16 = c * 4 + h * 2 + u;
                afr[c][rt].q[u] = *(const u32x4*)(
                    asb + rt * 8192 + l32 * 256 + ((o16 ^ (l32 & 7)) << 4));
            }

    #pragma unroll
    for (int tt = 0; tt < 16; ++tt) {
        const int sl = tt & 1;        // literal per unroll
        const float hc = hcs[(w * 16 + tt) * 32 + l32];
        f32x16 acc[2];                // [rt]; all elements are col=l32 -> same code
        #pragma unroll
        for (int r = 0; r < 16; r++) { acc[0][r] = -hc; acc[1][r] = -hc; }

        // 8 MX MFMAs (K=64 each): 2 chains x 4 deep, interleaved
        #pragma unroll
        for (int c = 0; c < 4; c++)
            #pragma unroll
            for (int rt = 0; rt < 2; rt++)
                acc[rt] = __builtin_amdgcn_mfma_scale_f32_32x32x64_f8f6f4(
                    afr[c][rt].v8, bfr[sl][c].v8, acc[rt],
                    0, 0,            // cbsz/blgp: fp8 e4m3 both
                    0, 127,          // opsel_a, scale_a = 2^0
                    0, 127);         // opsel_b, scale_b = 2^0

        // refill slot with tile tt+2 (after reads; SSA renames)
        if (tt + 2 < 16) {
            #pragma unroll
            for (int c = 0; c < 4; c++)
                #pragma unroll
                for (int u = 0; u < 2; u++)
                    bfr[sl][c].q[u] = *(const u32x4*)(
                        bbase + (tt + 2) * 8192 + c * 2048 + u * 1024);
        }

        // fold tile into running max (pack 11-bit code id into low mantissa)
        const unsigned code = (unsigned)((w * 16 + tt) * 32 + l32);
        #pragma unroll
        for (int rt = 0; rt < 2; rt++)
            #pragma unroll
            for (int r = 0; r < 16; r++) {
                unsigned u = (__float_as_uint(acc[rt][r]) & 0xFFFFF800u) | code;
                mp[rt][r] = fmaxf(mp[rt][r], __uint_as_float(u));
            }
    }

    // ---- cross-lane argmax over the 32 lanes sharing each output row ----
    #pragma unroll
    for (int m = 1; m <= 16; m <<= 1)
        #pragma unroll
        for (int rt = 0; rt < 2; rt++)
            #pragma unroll
            for (int r = 0; r < 16; r++)
                mp[rt][r] = fmaxf(mp[rt][r], __shfl_xor(mp[rt][r], m, 64));

    __syncthreads();                  // everyone past As reads (overlay safe)

    if (l32 == 0) {
        #pragma unroll
        for (int rt = 0; rt < 2; rt++)
            #pragma unroll
            for (int r = 0; r < 16; r++) {
                const int row = rt * 32 + (r & 3) + 8 * (r >> 2) + 4 * h;   // 0..63
                tl->red[row][w] = mp[rt][r];
            }
    }
    __syncthreads();
    if (t < BROWS) {
        float b0 = fmaxf(fmaxf(tl->red[t][0], tl->red[t][1]),
                         fmaxf(tl->red[t][2], tl->red[t][3]));
        tl->idxs[t] = (int)(__float_as_uint(b0) & 2047u);
    }
    __syncthreads();

    // ---- fused gather (fp32 codebook) + loss partial ----
    float lsum = 0.0f;
    #pragma unroll 4
    for (int r = 0; r < BROWS; r++) {
        const int code = tl->idxs[r];
        const float c  = cb[(size_t)code * DIM + t];
        const float xv = x[(size_t)(row0 + r) * DIM + t];
        out[(size_t)(row0 + r) * DIM + t] = c;
        const float d = xv - c;
        lsum += d * d;
    }
    #pragma unroll
    for (int o = 32; o > 0; o >>= 1) lsum += __shfl_down(lsum, o, 64);
    if (lane == 0) tl->lred[w] = lsum;
    __syncthreads();
    if (t == 0) {
        const float scale = 1.25f / (float)((size_t)N_ROWS * DIM);  // (beta+1)/(N*D)
        atomicAdd(loss, (tl->lred[0] + tl->lred[1] + tl->lred[2] + tl->lred[3]) * scale);
    }
}

extern "C" void kernel_launch(void* const* d_in, const int* in_sizes, int n_in,
                              void* d_out, int out_size, void* d_ws, size_t ws_size,
                              hipStream_t stream) {
    const float* x  = (const float*)d_in[0];
    const float* cb = (const float*)d_in[1];
    float* out  = (float*)d_out;
    float* loss = out + (size_t)N_ROWS * DIM;

    char* ws = (char*)d_ws;
    uint4* cbF    = (uint4*)ws;                                    // 512 KB
    float* halfcn = (float*)(ws + (size_t)KCODES * 256);           // 8 KB

    prep_all<<<KCODES / 4, 256, 0, stream>>>(cb, cbF, halfcn, loss);
    vq_fused<<<N_ROWS / BROWS, 256, 0, stream>>>(x, cb, cbF, halfcn, out, loss);
}